// Round 5
// baseline (2232.828 us; speedup 1.0000x reference)
//
#include <hip/hip_runtime.h>
#include <hip/hip_cooperative_groups.h>
#include <math.h>

namespace cg = cooperative_groups;

// Problem constants (match reference)
#define NT_     64000
#define E_      400000
#define B_      128
#define L_      50
#define KD_     256     // K*D
#define D_      64
#define N_USER_ 100000
#define MAXN_   (B_*L_ + B_)   // 6528 max distinct head nodes

// ---------------- wave helpers ----------------
__device__ __forceinline__ float wred(float v){
#pragma unroll
  for(int s=32;s;s>>=1) v += __shfl_xor(v, s, 64);
  return v;
}
__device__ __forceinline__ int wredi(int v){
#pragma unroll
  for(int s=32;s;s>>=1) v += __shfl_xor(v, s, 64);
  return v;
}

// ---------------- threefry2x32 (JAX key(1) == (0,1)), partitionable XOR-fold ----------------
__device__ __forceinline__ unsigned rotl(unsigned x, int r){ return (x<<r)|(x>>(32-r)); }

__device__ void tf2x32(unsigned c0, unsigned c1, unsigned &o0, unsigned &o1){
  const unsigned k0=0u, k1=1u;
  const unsigned k2=k0^k1^0x1BD11BDAu;
  unsigned x0=c0+k0, x1=c1+k1;
  const int RA[4]={13,15,26,6};
  const int RB[4]={17,29,16,24};
#pragma unroll
  for(int i=0;i<4;i++){ x0+=x1; x1=rotl(x1,RA[i]); x1^=x0; }
  x0+=k1; x1+=k2+1u;
#pragma unroll
  for(int i=0;i<4;i++){ x0+=x1; x1=rotl(x1,RB[i]); x1^=x0; }
  x0+=k2; x1+=k0+2u;
#pragma unroll
  for(int i=0;i<4;i++){ x0+=x1; x1=rotl(x1,RA[i]); x1^=x0; }
  x0+=k0; x1+=k1+3u;
#pragma unroll
  for(int i=0;i<4;i++){ x0+=x1; x1=rotl(x1,RB[i]); x1^=x0; }
  x0+=k1; x1+=k2+4u;
#pragma unroll
  for(int i=0;i<4;i++){ x0+=x1; x1=rotl(x1,RA[i]); x1^=x0; }
  x0+=k2; x1+=k0+5u;
  o0=x0; o1=x1;
}

__device__ float gumbel_at(int idx){
  unsigned o0,o1;
  tf2x32(0u, (unsigned)idx, o0, o1);      // counts uint64 iota: hi=0, lo=idx
  unsigned bits = o0 ^ o1;                 // 32-bit XOR fold (partitionable)
  unsigned fb = (bits>>9) | 0x3f800000u;   // [1,2)
  float f = __uint_as_float(fb) - 1.0f;    // [0,1)
  const float mn=1e-4f, mx=1.0f-1e-4f;
  float u = fmaxf(mn, f*(mx-mn)+mn);
  return -logf(-logf(u));
}

// ---------------- mega-kernel parameter block ----------------
struct MP {
  const float *embed, *delta, *tau_p, *W1, *W2, *seqs_time, *clk_time;
  const int *uid, *sid, *node_ids, *row, *col, *seq_map, *tar_map, *seq_idx, *seq_len;
  float* out;
  float *acc, *mu, *dinv, *wgt, *x2c, *x0, *x1;
  int *ncount, *cnt, *need, *markpos, *bsum, *nlist, *cur, *offs, *src;
};

__global__ __launch_bounds__(256, 8) void mega(MP p){
  cg::grid_group g = cg::this_grid();
  const int t = threadIdx.x;
  const int tid = blockIdx.x*256 + t;
  const int nthr = gridDim.x*256;
  const int lane = t & 63;
  const int kq   = t >> 6;
  __shared__ float shf[24];
  __shared__ int   shi[4];

  // ---- P0: init (replaces memsets) ----
  for(int i = tid; i < NT_; i += nthr){ p.markpos[i] = -1; p.cnt[i] = 0; p.need[i] = 0; }
  if(tid < B_*4) p.acc[tid] = 0.f;
  if(tid == 0) *p.ncount = 0;
  g.sync();

  // ---- P1: head-node dedup  +  P2: x0 gather + degree count (independent) ----
  if(tid < MAXN_){
    int n = (tid < B_*L_) ? p.seq_map[tid] : p.tar_map[tid - B_*L_];
    int old = atomicCAS(&p.markpos[n], -1, -2);
    if(old == -1){
      int s = atomicAdd(p.ncount, 1);
      p.nlist[s] = n;
      p.need[n] = 1;
      __threadfence();
      p.markpos[n] = s;
    }
  }
  {
    const float4* embed4 = (const float4*)p.embed;
    float4* x04 = (float4*)p.x0;
    for(int i = tid; i < NT_*64; i += nthr){
      int node = i>>6, q = i&63;
      x04[i] = embed4[(size_t)p.node_ids[node]*64 + q];
    }
    for(int e = tid; e < E_; e += nthr) atomicAdd(&p.cnt[p.col[e]], 1);
  }
  g.sync();

  // ---- P3a: per-256-chunk sums ----
  if(blockIdx.x < NT_/256){
    int v = wredi(p.cnt[blockIdx.x*256 + t]);
    if(lane==0) shi[kq] = v;
    __syncthreads();
    if(t==0) p.bsum[blockIdx.x] = shi[0]+shi[1]+shi[2]+shi[3];
  }
  g.sync();

  // ---- P3b: exclusive scan of 250 block sums (block 0) ----
  if(blockIdx.x == 0){
    const int nb = NT_/256;
    int v = (t<nb)? p.bsum[t] : 0;
    int s = v;
#pragma unroll
    for(int d=1; d<64; d<<=1){ int tt = __shfl_up(s, d, 64); if(lane>=d) s += tt; }
    __syncthreads();
    if(lane==63) shi[kq] = s;
    __syncthreads();
    int add=0;
    for(int w=0; w<kq; w++) add += shi[w];
    if(t<nb) p.bsum[t] = add + s - v;
  }
  g.sync();

  // ---- P3c: offs + cur + dinv ----
  if(blockIdx.x < NT_/256){
    int i = blockIdx.x*256 + t;
    int v = p.cnt[i];
    int s = v;
#pragma unroll
    for(int d=1; d<64; d<<=1){ int tt = __shfl_up(s, d, 64); if(lane>=d) s += tt; }
    __syncthreads();
    if(lane==63) shi[kq] = s;
    __syncthreads();
    int add = p.bsum[blockIdx.x];
    for(int w=0; w<kq; w++) add += shi[w];
    int off0 = add + s - v;
    p.offs[i] = off0;
    p.cur[i]  = off0;
    p.dinv[i] = (v>0)? (1.0f/sqrtf((float)v)) : 0.0f;
    if(i == NT_-1) p.offs[NT_] = add + s;
  }
  g.sync();

  // ---- P4: fill CSR (src,wgt) + need propagation ----
  for(int e = tid; e < E_; e += nthr){
    int c = p.col[e], r = p.row[e];
    int slot = atomicAdd(&p.cur[c], 1);
    p.src[slot] = r;
    p.wgt[slot] = p.dinv[r]*p.dinv[c]*0.25f;
    if(p.markpos[c] != -1) p.need[r] = 1;
  }
  g.sync();

  // ---- P5: conv1 aggregate (wave per needed node) ----
  {
    const float4* x04 = (const float4*)p.x0;
    float4* x14 = (float4*)p.x1;
    int wave = blockIdx.x*4 + kq;
    int nwaves = gridDim.x*4;
    for(int c = wave; c < NT_; c += nwaves){
      if(!p.need[c]) continue;
      float4 acc = {0.f,0.f,0.f,0.f};
      int s = p.offs[c], e = p.offs[c+1];
      int i = s;
      for(; i+4<=e; i+=4){
        int   s0=p.src[i],  s1=p.src[i+1], s2=p.src[i+2], s3=p.src[i+3];
        float w0=p.wgt[i],  w1=p.wgt[i+1], w2=p.wgt[i+2], w3=p.wgt[i+3];
        float4 v0=x04[(size_t)s0*64+lane];
        float4 v1=x04[(size_t)s1*64+lane];
        float4 v2=x04[(size_t)s2*64+lane];
        float4 v3=x04[(size_t)s3*64+lane];
        acc.x = fmaf(v0.x,w0,fmaf(v1.x,w1,fmaf(v2.x,w2,fmaf(v3.x,w3,acc.x))));
        acc.y = fmaf(v0.y,w0,fmaf(v1.y,w1,fmaf(v2.y,w2,fmaf(v3.y,w3,acc.y))));
        acc.z = fmaf(v0.z,w0,fmaf(v1.z,w1,fmaf(v2.z,w2,fmaf(v3.z,w3,acc.z))));
        acc.w = fmaf(v0.w,w0,fmaf(v1.w,w1,fmaf(v2.w,w2,fmaf(v3.w,w3,acc.w))));
      }
      for(; i<e; i++){
        int s0=p.src[i]; float w0=p.wgt[i];
        float4 v0=x04[(size_t)s0*64+lane];
        acc.x=fmaf(v0.x,w0,acc.x); acc.y=fmaf(v0.y,w0,acc.y);
        acc.z=fmaf(v0.z,w0,acc.z); acc.w=fmaf(v0.w,w0,acc.w);
      }
      x14[(size_t)c*64+lane] = acc;
    }
  }
  g.sync();

  // ---- P6: conv2 fused (block per head node, grid-stride) ----
  {
    int nc = *p.ncount;
    for(int slot = blockIdx.x; slot < nc; slot += gridDim.x){
      int c = p.nlist[slot];
      float tx = tanhf(p.x1[(size_t)c*KD_ + t]);
      float acc = 0.f;
      int s = p.offs[c], e = p.offs[c+1];
      for(int i=s;i<e;i++){
        int r = p.src[i];
        float xr = p.x1[(size_t)r*KD_ + t];
        float zk = wred(xr*tx);
        if(lane==0) shf[kq] = zk;
        __syncthreads();
        float z0=shf[0], z1=shf[1], z2=shf[2], z3=shf[3];
        float m = fmaxf(fmaxf(z0,z1), fmaxf(z2,z3));
        float e0=expf(z0-m), e1=expf(z1-m), e2=expf(z2-m), e3=expf(z3-m);
        float inv = (4.f*p.wgt[i])/(e0+e1+e2+e3);   // base = 4*wgt
        float w = ((kq==0)?e0:(kq==1)?e1:(kq==2)?e2:e3) * inv;
        acc = fmaf(xr, w, acc);
        __syncthreads();
      }
      p.x2c[(size_t)slot*KD_ + t] = acc;
    }
  }
  g.sync();

  // ---- P7: head (block per (b,l), grid-stride) ----
  for(int bl = blockIdx.x; bl < B_*L_; bl += gridDim.x){
    int b = bl / L_, l = bl % L_;
    if(l < p.seq_len[b]){
      float xt = p.x2c[(size_t)p.markpos[p.tar_map[b]]*KD_ + t];
      float av = p.embed[((size_t)(N_USER_ + p.sid[b]))*KD_ + t];
      const float* w2row = p.W2 + lane*64;
#pragma unroll 8
      for(int d=0; d<64; d++) av = fmaf(__shfl(xt, d, 64), w2row[d], av);
      float au = p.embed[(size_t)p.uid[b]*KD_ + t];
      int n = p.seq_map[bl];
      float xv = p.x2c[(size_t)p.markpos[n]*KD_ + t];
      float se = p.embed[(size_t)p.node_ids[n]*KD_ + t];
      const float* w1row = p.W1 + lane*64;
#pragma unroll 8
      for(int d=0; d<64; d++) se = fmaf(__shfl(xv, d, 64), w1row[d], se);
      float nv  = wred(av*av);
      float nu  = wred(au*au);
      float duv = wred(av*au);
      float dv  = wred(se*av);
      float du  = wred(se*au);
      float ns  = wred(se*se);
      if(lane==0){ shf[0*4+kq]=nv; shf[1*4+kq]=nu; shf[2*4+kq]=duv;
                   shf[3*4+kq]=dv; shf[4*4+kq]=du; shf[5*4+kq]=ns; }
      __syncthreads();
      if(t==0){
        float jv  = expf(-(p.clk_time[b]-p.seqs_time[bl]) * (1.0f/1000.0f) * p.delta[p.uid[b]]);
        float tau = p.tau_p[p.seq_idx[bl]];
        float gam[4], lg[4];
        float m = -1e30f;
#pragma unroll
        for(int kk=0;kk<4;kk++){
          float rnv = fmaxf(sqrtf(shf[0*4+kk]), 1e-8f);
          float rnu = fmaxf(sqrtf(shf[1*4+kk]), 1e-8f);
          float ins = 1.f/fmaxf(sqrtf(shf[5*4+kk]), 1e-8f);
          if(l==0) p.mu[b*4+kk] = shf[2*4+kk]/(rnv*rnu);
          gam[kk] = shf[3*4+kk]*ins/rnv;
          float logit = shf[4*4+kk]*ins/rnu;
          lg[kk] = (logit + gumbel_at(bl*4+kk))/tau;
          m = fmaxf(m, lg[kk]);
        }
        float es[4], ssum=0.f;
#pragma unroll
        for(int kk=0;kk<4;kk++){ es[kk]=expf(lg[kk]-m); ssum+=es[kk]; }
        float isum = 1.f/ssum;
#pragma unroll
        for(int kk=0;kk<4;kk++)
          atomicAdd(&p.acc[b*4+kk], jv * gam[kk] * es[kk]*isum);
      }
      __syncthreads();
    }
  }
  g.sync();

  // ---- P8: finalize ----
  if(blockIdx.x == 0 && t < B_){
    float s = 0.f;
#pragma unroll
    for(int k=0;k<4;k++) s += p.mu[t*4+k] + p.acc[t*4+k];
    p.out[t] = s * 0.25f;
  }
}

// ================= fallback multi-kernel path (round-4, known-good) =================
__global__ void mark_assign_k(const int* __restrict__ seq_map, const int* __restrict__ tar_map,
                              int* __restrict__ markpos, int* __restrict__ nlist,
                              int* __restrict__ ncount, int* __restrict__ need){
  int pgl = blockIdx.x*256 + threadIdx.x;
  if(pgl >= MAXN_) return;
  int n = (pgl < B_*L_) ? seq_map[pgl] : tar_map[pgl - B_*L_];
  int old = atomicCAS(&markpos[n], -1, -2);
  if(old == -1){
    int s = atomicAdd(ncount, 1);
    nlist[s] = n; need[n] = 1;
    __threadfence();
    markpos[n] = s;
  }
}
__global__ void gather_count_k(const float4* __restrict__ embed4, const int* __restrict__ node_ids,
                               const int* __restrict__ col, float4* __restrict__ x04,
                               int* __restrict__ cnt){
  int i = blockIdx.x*256 + threadIdx.x;
  int node = i>>6, q = i&63;
  x04[i] = embed4[(size_t)node_ids[node]*64 + q];
  if(i < E_) atomicAdd(&cnt[col[i]], 1);
}
__global__ void block_sums_k(const int* __restrict__ cnt, int* __restrict__ bsum){
  int i = blockIdx.x*256 + threadIdx.x;
  int v = wredi(cnt[i]);
  __shared__ int ws[4];
  if((threadIdx.x&63)==0) ws[threadIdx.x>>6]=v;
  __syncthreads();
  if(threadIdx.x==0) bsum[blockIdx.x]=ws[0]+ws[1]+ws[2]+ws[3];
}
__global__ void scan_bsum_k(int* __restrict__ bsum){
  const int nb = NT_/256;
  int i = threadIdx.x;
  int v = (i<nb)? bsum[i] : 0;
  int lane = i&63, wv = i>>6;
  int s = v;
#pragma unroll
  for(int d=1; d<64; d<<=1){ int t = __shfl_up(s, d, 64); if(lane>=d) s += t; }
  __shared__ int ws[4];
  if(lane==63) ws[wv]=s;
  __syncthreads();
  int add=0;
  for(int w=0;w<wv;w++) add += ws[w];
  if(i<nb) bsum[i] = add + s - v;
}
__global__ void scan_final_k(const int* __restrict__ cnt, const int* __restrict__ bsumx,
                             int* __restrict__ offs, int* __restrict__ cur,
                             float* __restrict__ dinv){
  int i = blockIdx.x*256 + threadIdx.x;
  int v = cnt[i];
  int lane = threadIdx.x&63, wv = threadIdx.x>>6;
  int s = v;
#pragma unroll
  for(int d=1; d<64; d<<=1){ int t = __shfl_up(s, d, 64); if(lane>=d) s += t; }
  __shared__ int ws[4];
  if(lane==63) ws[wv]=s;
  __syncthreads();
  int add = bsumx[blockIdx.x];
  for(int w=0;w<wv;w++) add += ws[w];
  int off0 = add + s - v;
  offs[i] = off0; cur[i] = off0;
  dinv[i] = (v>0)? (1.0f/sqrtf((float)v)) : 0.0f;
  if(i == NT_-1) offs[NT_] = add + s;
}
__global__ void fill_csr_k(const int* __restrict__ row, const int* __restrict__ col,
                           const float* __restrict__ dinv, const int* __restrict__ markpos,
                           int* __restrict__ cur, int* __restrict__ src, float* __restrict__ wgt,
                           int* __restrict__ need){
  int e = blockIdx.x*256 + threadIdx.x;
  if(e<E_){
    int c = col[e], r = row[e];
    int slot = atomicAdd(&cur[c], 1);
    src[slot] = r;
    wgt[slot] = dinv[r]*dinv[c]*0.25f;
    if(markpos[c] != -1) need[r] = 1;
  }
}
__global__ void aggregate1_k(const float4* __restrict__ x04, const int* __restrict__ offs,
                             const int* __restrict__ src, const float* __restrict__ wgt,
                             const int* __restrict__ need, float4* __restrict__ x14){
  int wv = threadIdx.x>>6, lane = threadIdx.x&63;
  int c = blockIdx.x*4 + wv;
  if(!need[c]) return;
  float4 acc = {0.f,0.f,0.f,0.f};
  int s = offs[c], e = offs[c+1];
  int i = s;
  for(; i+4<=e; i+=4){
    int   s0=src[i],   s1=src[i+1], s2=src[i+2], s3=src[i+3];
    float w0=wgt[i],   w1=wgt[i+1], w2=wgt[i+2], w3=wgt[i+3];
    float4 v0=x04[(size_t)s0*64+lane];
    float4 v1=x04[(size_t)s1*64+lane];
    float4 v2=x04[(size_t)s2*64+lane];
    float4 v3=x04[(size_t)s3*64+lane];
    acc.x = fmaf(v0.x,w0,fmaf(v1.x,w1,fmaf(v2.x,w2,fmaf(v3.x,w3,acc.x))));
    acc.y = fmaf(v0.y,w0,fmaf(v1.y,w1,fmaf(v2.y,w2,fmaf(v3.y,w3,acc.y))));
    acc.z = fmaf(v0.z,w0,fmaf(v1.z,w1,fmaf(v2.z,w2,fmaf(v3.z,w3,acc.z))));
    acc.w = fmaf(v0.w,w0,fmaf(v1.w,w1,fmaf(v2.w,w2,fmaf(v3.w,w3,acc.w))));
  }
  for(; i<e; i++){
    int s0=src[i]; float w0=wgt[i];
    float4 v0=x04[(size_t)s0*64+lane];
    acc.x=fmaf(v0.x,w0,acc.x); acc.y=fmaf(v0.y,w0,acc.y);
    acc.z=fmaf(v0.z,w0,acc.z); acc.w=fmaf(v0.w,w0,acc.w);
  }
  x14[(size_t)c*64+lane] = acc;
}
__global__ void conv2_fused_k(const float* __restrict__ x1, const int* __restrict__ offs,
                              const int* __restrict__ src, const float* __restrict__ wgt,
                              const int* __restrict__ nlist, const int* __restrict__ ncount,
                              float* __restrict__ x2c){
  int slot = blockIdx.x;
  if(slot >= *ncount) return;
  int c = nlist[slot];
  int t = threadIdx.x, k = t>>6, lane = t&63;
  float tx = tanhf(x1[(size_t)c*KD_ + t]);
  float acc = 0.f;
  __shared__ float zs[4];
  int s = offs[c], e = offs[c+1];
  for(int i=s;i<e;i++){
    int r = src[i];
    float xr = x1[(size_t)r*KD_ + t];
    float zk = wred(xr*tx);
    if(lane==0) zs[k] = zk;
    __syncthreads();
    float z0=zs[0], z1=zs[1], z2=zs[2], z3=zs[3];
    float m = fmaxf(fmaxf(z0,z1), fmaxf(z2,z3));
    float e0=expf(z0-m), e1=expf(z1-m), e2=expf(z2-m), e3=expf(z3-m);
    float inv = (4.f*wgt[i])/(e0+e1+e2+e3);
    float w = ((k==0)?e0:(k==1)?e1:(k==2)?e2:e3) * inv;
    acc = fmaf(xr, w, acc);
    __syncthreads();
  }
  x2c[(size_t)slot*KD_ + t] = acc;
}
__global__ void head_fused_k(const float* __restrict__ embed, const float* __restrict__ x2c,
                             const int* __restrict__ markpos,
                             const float* __restrict__ W1, const float* __restrict__ W2,
                             const int* __restrict__ node_ids, const int* __restrict__ seq_map,
                             const int* __restrict__ tar_map, const int* __restrict__ seq_idx,
                             const int* __restrict__ seq_len,
                             const int* __restrict__ uid, const int* __restrict__ sid,
                             const float* __restrict__ seqs_time, const float* __restrict__ clk_time,
                             const float* __restrict__ tau_p, const float* __restrict__ delta,
                             float* __restrict__ mu, float* __restrict__ acc){
  int bl = blockIdx.x;
  int b = bl / L_, l = bl % L_;
  if(l >= seq_len[b]) return;
  int t = threadIdx.x, k = t>>6, lane = t&63;
  float xt = x2c[(size_t)markpos[tar_map[b]]*KD_ + t];
  float av = embed[((size_t)(N_USER_ + sid[b]))*KD_ + t];
  const float* w2row = W2 + lane*64;
#pragma unroll 8
  for(int d=0; d<64; d++) av = fmaf(__shfl(xt, d, 64), w2row[d], av);
  float au = embed[(size_t)uid[b]*KD_ + t];
  int n = seq_map[bl];
  float xv = x2c[(size_t)markpos[n]*KD_ + t];
  float se = embed[(size_t)node_ids[n]*KD_ + t];
  const float* w1row = W1 + lane*64;
#pragma unroll 8
  for(int d=0; d<64; d++) se = fmaf(__shfl(xv, d, 64), w1row[d], se);
  float nv  = wred(av*av);
  float nu  = wred(au*au);
  float duv = wred(av*au);
  float dv  = wred(se*av);
  float du  = wred(se*au);
  float ns  = wred(se*se);
  __shared__ float s6[6][4];
  if(lane==0){ s6[0][k]=nv; s6[1][k]=nu; s6[2][k]=duv; s6[3][k]=dv; s6[4][k]=du; s6[5][k]=ns; }
  __syncthreads();
  if(t==0){
    float jv  = expf(-(clk_time[b]-seqs_time[bl]) * (1.0f/1000.0f) * delta[uid[b]]);
    float tau = tau_p[seq_idx[bl]];
    float gam[4], lg[4];
    float m = -1e30f;
#pragma unroll
    for(int kk=0;kk<4;kk++){
      float rnv = fmaxf(sqrtf(s6[0][kk]), 1e-8f);
      float rnu = fmaxf(sqrtf(s6[1][kk]), 1e-8f);
      float ins = 1.f/fmaxf(sqrtf(s6[5][kk]), 1e-8f);
      if(l==0) mu[b*4+kk] = s6[2][kk]/(rnv*rnu);
      gam[kk] = s6[3][kk]*ins/rnv;
      float logit = s6[4][kk]*ins/rnu;
      lg[kk] = (logit + gumbel_at(bl*4+kk))/tau;
      m = fmaxf(m, lg[kk]);
    }
    float es[4], ssum=0.f;
#pragma unroll
    for(int kk=0;kk<4;kk++){ es[kk]=expf(lg[kk]-m); ssum+=es[kk]; }
    float isum = 1.f/ssum;
#pragma unroll
    for(int kk=0;kk<4;kk++)
      atomicAdd(&acc[b*4+kk], jv * gam[kk] * es[kk]*isum);
  }
}
__global__ void finalize_k(const float* __restrict__ mu, const float* __restrict__ acc,
                           float* __restrict__ out){
  int b = threadIdx.x;
  if(b < B_){
    float s = 0.f;
#pragma unroll
    for(int k=0;k<4;k++) s += mu[b*4+k] + acc[b*4+k];
    out[b] = s * 0.25f;
  }
}

// ---------------- launch ----------------
extern "C" void kernel_launch(void* const* d_in, const int* in_sizes, int n_in,
                              void* d_out, int out_size, void* d_ws, size_t ws_size,
                              hipStream_t stream){
  const float* embed = (const float*)d_in[0];
  const float* delta = (const float*)d_in[1];
  const float* tau_p = (const float*)d_in[2];
  const float* W1    = (const float*)d_in[3];
  const float* W2    = (const float*)d_in[4];
  const float* seqs_time = (const float*)d_in[5];
  const float* clk_time  = (const float*)d_in[6];
  const int* uid      = (const int*)d_in[7];
  const int* sid      = (const int*)d_in[8];
  const int* node_ids = (const int*)d_in[9];
  const int* edge_index = (const int*)d_in[10];
  const int* seq_map  = (const int*)d_in[11];
  const int* tar_map  = (const int*)d_in[12];
  const int* seq_idx  = (const int*)d_in[13];
  const int* seq_len  = (const int*)d_in[14];
  const int* row = edge_index;
  const int* col = edge_index + E_;
  float* out = (float*)d_out;

  char* wp = (char*)d_ws;
  size_t o = 0;
  auto carve = [&](size_t bytes)->char*{ char* r = wp + o; o = (o + bytes + 255) & ~(size_t)255; return r; };
  float* acc    = (float*)carve((size_t)B_*4*4);
  int*   ncount = (int*)  carve((size_t)4);
  int*   cnt    = (int*)  carve((size_t)NT_*4);
  int*   need   = (int*)  carve((size_t)NT_*4);
  char*  zero_end = wp + o;
  int*   markpos= (int*)  carve((size_t)NT_*4);
  float* mu     = (float*)carve((size_t)B_*4*4);
  int*   bsum   = (int*)  carve((size_t)256*4);
  int*   nlist  = (int*)  carve((size_t)MAXN_*4);
  float* dinv   = (float*)carve((size_t)NT_*4);
  int*   cur    = (int*)  carve((size_t)NT_*4);
  int*   offs   = (int*)  carve((size_t)(NT_+1)*4);
  int*   src    = (int*)  carve((size_t)E_*4);
  float* wgt    = (float*)carve((size_t)E_*4);
  float* x2c    = (float*)carve((size_t)MAXN_*KD_*4);
  float* x0     = (float*)carve((size_t)NT_*KD_*4);   // 64 MB
  float* x1     = (float*)carve((size_t)NT_*KD_*4);   // 64 MB

  MP p;
  p.embed=embed; p.delta=delta; p.tau_p=tau_p; p.W1=W1; p.W2=W2;
  p.seqs_time=seqs_time; p.clk_time=clk_time;
  p.uid=uid; p.sid=sid; p.node_ids=node_ids; p.row=row; p.col=col;
  p.seq_map=seq_map; p.tar_map=tar_map; p.seq_idx=seq_idx; p.seq_len=seq_len;
  p.out=out;
  p.acc=acc; p.mu=mu; p.dinv=dinv; p.wgt=wgt; p.x2c=x2c; p.x0=x0; p.x1=x1;
  p.ncount=ncount; p.cnt=cnt; p.need=need; p.markpos=markpos; p.bsum=bsum;
  p.nlist=nlist; p.cur=cur; p.offs=offs; p.src=src;

  void* args[] = { &p };
  hipError_t err = hipLaunchCooperativeKernel((const void*)mega, dim3(2048), dim3(256),
                                              args, 0, stream);
  if(err == hipSuccess) return;
  (void)hipGetLastError();   // clear; fall back to multi-kernel path

  hipMemsetAsync(acc, 0, (size_t)(zero_end - (char*)acc), stream);
  hipMemsetAsync(markpos, 0xFF, (size_t)NT_*4, stream);
  mark_assign_k<<<(MAXN_+255)/256, 256, 0, stream>>>(seq_map, tar_map, markpos, nlist, ncount, need);
  gather_count_k<<<NT_*64/256, 256, 0, stream>>>((const float4*)embed, node_ids, col,
                                                 (float4*)x0, cnt);
  block_sums_k<<<NT_/256, 256, 0, stream>>>(cnt, bsum);
  scan_bsum_k<<<1, 256, 0, stream>>>(bsum);
  scan_final_k<<<NT_/256, 256, 0, stream>>>(cnt, bsum, offs, cur, dinv);
  fill_csr_k<<<(E_+255)/256, 256, 0, stream>>>(row, col, dinv, markpos, cur, src, wgt, need);
  aggregate1_k<<<NT_/4, 256, 0, stream>>>((const float4*)x0, offs, src, wgt, need, (float4*)x1);
  conv2_fused_k<<<MAXN_, 256, 0, stream>>>(x1, offs, src, wgt, nlist, ncount, x2c);
  head_fused_k<<<B_*L_, 256, 0, stream>>>(embed, x2c, markpos, W1, W2,
                                          node_ids, seq_map, tar_map, seq_idx, seq_len,
                                          uid, sid, seqs_time, clk_time, tau_p, delta,
                                          mu, acc);
  finalize_k<<<1, 128, 0, stream>>>(mu, acc, out);
}

// Round 6
// 206.235 us; speedup vs baseline: 10.8266x; 10.8266x over previous
//
#include <hip/hip_runtime.h>
#include <math.h>

// Problem constants (match reference)
#define NT_     64000
#define E_      400000
#define B_      128
#define L_      50
#define KD_     256     // K*D
#define D_      64
#define N_USER_ 100000
#define MAXN_   (B_*L_ + B_)   // 6528 max distinct head nodes

// ---------------- wave helpers ----------------
__device__ __forceinline__ float wred(float v){
#pragma unroll
  for(int s=32;s;s>>=1) v += __shfl_xor(v, s, 64);
  return v;
}
__device__ __forceinline__ int wredi(int v){
#pragma unroll
  for(int s=32;s;s>>=1) v += __shfl_xor(v, s, 64);
  return v;
}

// ---------------- threefry2x32 (JAX key(1) == (0,1)), partitionable XOR-fold ----------------
__device__ __forceinline__ unsigned rotl(unsigned x, int r){ return (x<<r)|(x>>(32-r)); }

__device__ void tf2x32(unsigned c0, unsigned c1, unsigned &o0, unsigned &o1){
  const unsigned k0=0u, k1=1u;
  const unsigned k2=k0^k1^0x1BD11BDAu;
  unsigned x0=c0+k0, x1=c1+k1;
  const int RA[4]={13,15,26,6};
  const int RB[4]={17,29,16,24};
#pragma unroll
  for(int i=0;i<4;i++){ x0+=x1; x1=rotl(x1,RA[i]); x1^=x0; }
  x0+=k1; x1+=k2+1u;
#pragma unroll
  for(int i=0;i<4;i++){ x0+=x1; x1=rotl(x1,RB[i]); x1^=x0; }
  x0+=k2; x1+=k0+2u;
#pragma unroll
  for(int i=0;i<4;i++){ x0+=x1; x1=rotl(x1,RA[i]); x1^=x0; }
  x0+=k0; x1+=k1+3u;
#pragma unroll
  for(int i=0;i<4;i++){ x0+=x1; x1=rotl(x1,RB[i]); x1^=x0; }
  x0+=k1; x1+=k2+4u;
#pragma unroll
  for(int i=0;i<4;i++){ x0+=x1; x1=rotl(x1,RA[i]); x1^=x0; }
  x0+=k2; x1+=k0+5u;
  o0=x0; o1=x1;
}

__device__ float gumbel_at(int idx){
  unsigned o0,o1;
  tf2x32(0u, (unsigned)idx, o0, o1);      // counts uint64 iota: hi=0, lo=idx
  unsigned bits = o0 ^ o1;                 // 32-bit XOR fold (partitionable)
  unsigned fb = (bits>>9) | 0x3f800000u;   // [1,2)
  float f = __uint_as_float(fb) - 1.0f;    // [0,1)
  const float mn=1e-4f, mx=1.0f-1e-4f;
  float u = fmaxf(mn, f*(mx-mn)+mn);
  return -logf(-logf(u));
}

// ---------------- K1: head-node dedup + degree count (fused) ----------------
// markpos encoding: 0 = unassigned, s+1 = slot s (zero-memset friendly)
__global__ void mark_count(const int* __restrict__ seq_map, const int* __restrict__ tar_map,
                           const int* __restrict__ col,
                           int* __restrict__ markpos, int* __restrict__ nlist,
                           int* __restrict__ ncount, int* __restrict__ need,
                           int* __restrict__ cnt){
  int i = blockIdx.x*256 + threadIdx.x;
  if(i < MAXN_){
    int n = (i < B_*L_) ? seq_map[i] : tar_map[i - B_*L_];
    int old = atomicCAS(&markpos[n], 0, -1);
    if(old == 0){
      int s = atomicAdd(ncount, 1);
      nlist[s] = n;
      need[n] = 1;
      __threadfence();
      markpos[n] = s + 1;
    }
  }
  if(i < E_) atomicAdd(&cnt[col[i]], 1);
}

// ---------------- K2..K4: CSR scan ----------------
__global__ void block_sums(const int* __restrict__ cnt, int* __restrict__ bsum){
  int i = blockIdx.x*256 + threadIdx.x;   // NT_ multiple of 256
  int v = wredi(cnt[i]);
  __shared__ int ws[4];
  if((threadIdx.x&63)==0) ws[threadIdx.x>>6]=v;
  __syncthreads();
  if(threadIdx.x==0) bsum[blockIdx.x]=ws[0]+ws[1]+ws[2]+ws[3];
}

__global__ void scan_bsum(int* __restrict__ bsum){
  const int nb = NT_/256;                 // 250
  int i = threadIdx.x;
  int v = (i<nb)? bsum[i] : 0;
  int lane = i&63, wv = i>>6;
  int s = v;
#pragma unroll
  for(int d=1; d<64; d<<=1){ int t = __shfl_up(s, d, 64); if(lane>=d) s += t; }
  __shared__ int ws[4];
  if(lane==63) ws[wv]=s;
  __syncthreads();
  int add=0;
  for(int w=0;w<wv;w++) add += ws[w];
  if(i<nb) bsum[i] = add + s - v;         // exclusive scan of block sums
}

// offs (exclusive) + dinv, one pass. No cur: fill_csr bumps offs in place.
__global__ void scan_final(const int* __restrict__ cnt, const int* __restrict__ bsumx,
                           int* __restrict__ offs, float* __restrict__ dinv){
  int i = blockIdx.x*256 + threadIdx.x;
  int v = cnt[i];
  int lane = threadIdx.x&63, wv = threadIdx.x>>6;
  int s = v;
#pragma unroll
  for(int d=1; d<64; d<<=1){ int t = __shfl_up(s, d, 64); if(lane>=d) s += t; }
  __shared__ int ws[4];
  if(lane==63) ws[wv]=s;
  __syncthreads();
  int add = bsumx[blockIdx.x];
  for(int w=0;w<wv;w++) add += ws[w];
  offs[i] = add + s - v;
  dinv[i] = (v>0)? (1.0f/sqrtf((float)v)) : 0.0f;
}

// ---------------- K5: fill CSR. slot = atomicAdd(offs[c]); stores nid+row+wgt ----------------
// After this kernel: offs[c] = INCLUSIVE prefix (end); start = offs[c]-cnt[c].
__global__ void fill_csr(const int* __restrict__ row, const int* __restrict__ col,
                         const int* __restrict__ node_ids, const float* __restrict__ dinv,
                         const int* __restrict__ markpos,
                         int* __restrict__ offs, int* __restrict__ src_nid,
                         int* __restrict__ src_row, float* __restrict__ wgt,
                         int* __restrict__ need){
  int e = blockIdx.x*256 + threadIdx.x;
  if(e<E_){
    int c = col[e], r = row[e];
    int slot = atomicAdd(&offs[c], 1);
    src_row[slot] = r;
    src_nid[slot] = node_ids[r];
    wgt[slot] = dinv[r]*dinv[c]*0.25f;
    if(markpos[c] != 0) need[r] = 1;     // x1[r] will be read by conv2
  }
}

// ---------------- K6: conv1 (filtered): wave-per-node, reads embed[src_nid] directly ----------------
__global__ void aggregate1(const float4* __restrict__ embed4, const int* __restrict__ offs,
                           const int* __restrict__ cnt, const int* __restrict__ src_nid,
                           const float* __restrict__ wgt, const int* __restrict__ need,
                           float4* __restrict__ x14){
  int wv = threadIdx.x>>6, lane = threadIdx.x&63;
  int c = blockIdx.x*4 + wv;
  if(!need[c]) return;                    // x1[c] never read downstream
  int e = offs[c];                        // inclusive end (post-fill)
  int s = e - cnt[c];
  float4 acc = {0.f,0.f,0.f,0.f};
  int i = s;
  for(; i+4<=e; i+=4){
    int   s0=src_nid[i], s1=src_nid[i+1], s2=src_nid[i+2], s3=src_nid[i+3];
    float w0=wgt[i],     w1=wgt[i+1],     w2=wgt[i+2],     w3=wgt[i+3];
    float4 v0=embed4[(size_t)s0*64+lane];
    float4 v1=embed4[(size_t)s1*64+lane];
    float4 v2=embed4[(size_t)s2*64+lane];
    float4 v3=embed4[(size_t)s3*64+lane];
    acc.x = fmaf(v0.x,w0,fmaf(v1.x,w1,fmaf(v2.x,w2,fmaf(v3.x,w3,acc.x))));
    acc.y = fmaf(v0.y,w0,fmaf(v1.y,w1,fmaf(v2.y,w2,fmaf(v3.y,w3,acc.y))));
    acc.z = fmaf(v0.z,w0,fmaf(v1.z,w1,fmaf(v2.z,w2,fmaf(v3.z,w3,acc.z))));
    acc.w = fmaf(v0.w,w0,fmaf(v1.w,w1,fmaf(v2.w,w2,fmaf(v3.w,w3,acc.w))));
  }
  for(; i<e; i++){
    int s0=src_nid[i]; float w0=wgt[i];
    float4 v0=embed4[(size_t)s0*64+lane];
    acc.x=fmaf(v0.x,w0,acc.x); acc.y=fmaf(v0.y,w0,acc.y);
    acc.z=fmaf(v0.z,w0,acc.z); acc.w=fmaf(v0.w,w0,acc.w);
  }
  x14[(size_t)c*64+lane] = acc;
}

// ---------------- K7: conv2 fused (only head nodes): z -> softmax -> aggregate ----------------
__global__ void conv2_fused(const float* __restrict__ x1, const int* __restrict__ offs,
                            const int* __restrict__ cnt, const int* __restrict__ src_row,
                            const float* __restrict__ wgt,
                            const int* __restrict__ nlist, const int* __restrict__ ncount,
                            float* __restrict__ x2c){
  int slot = blockIdx.x;
  if(slot >= *ncount) return;
  int c = nlist[slot];
  int t = threadIdx.x, k = t>>6, lane = t&63;
  float tx = tanhf(x1[(size_t)c*KD_ + t]);
  float acc = 0.f;
  __shared__ float zs[4];
  int e = offs[c];
  int s = e - cnt[c];
  for(int i=s;i<e;i++){
    int r = src_row[i];
    float xr = x1[(size_t)r*KD_ + t];
    float zk = wred(xr*tx);               // z[e,k] = dot(x1[row,k,:], tanh(x1[col,k,:]))
    if(lane==0) zs[k] = zk;
    __syncthreads();
    float z0=zs[0], z1=zs[1], z2=zs[2], z3=zs[3];
    // softmax(1+z) over k == softmax(z) (shift-invariant)
    float m = fmaxf(fmaxf(z0,z1), fmaxf(z2,z3));
    float e0=expf(z0-m), e1=expf(z1-m), e2=expf(z2-m), e3=expf(z3-m);
    float inv = (4.f*wgt[i])/(e0+e1+e2+e3);   // base = 4*wgt
    float w = ((k==0)?e0:(k==1)?e1:(k==2)?e2:e3) * inv;
    acc = fmaf(xr, w, acc);
    __syncthreads();
  }
  x2c[(size_t)slot*KD_ + t] = acc;
}

// ---------------- K8: head (prep_av folded into per-(b,l) block) ----------------
__global__ void head_fused(const float* __restrict__ embed, const float* __restrict__ x2c,
                           const int* __restrict__ markpos,
                           const float* __restrict__ W1, const float* __restrict__ W2,
                           const int* __restrict__ node_ids, const int* __restrict__ seq_map,
                           const int* __restrict__ tar_map, const int* __restrict__ seq_idx,
                           const int* __restrict__ seq_len,
                           const int* __restrict__ uid, const int* __restrict__ sid,
                           const float* __restrict__ seqs_time, const float* __restrict__ clk_time,
                           const float* __restrict__ tau_p, const float* __restrict__ delta,
                           float* __restrict__ mu, float* __restrict__ acc){
  int bl = blockIdx.x;
  int b = bl / L_, l = bl % L_;
  if(l >= seq_len[b]) return;           // masked position contributes exactly 0
  int t = threadIdx.x, k = t>>6, lane = t&63;
  // a_v = x2[tar] @ W2^T + embed[sid+N_USER]   (recomputed per block; 64 shfl-FMAs)
  float xt = x2c[(size_t)(markpos[tar_map[b]]-1)*KD_ + t];
  float av = embed[((size_t)(N_USER_ + sid[b]))*KD_ + t];
  const float* w2row = W2 + lane*64;
#pragma unroll 8
  for(int d=0; d<64; d++) av = fmaf(__shfl(xt, d, 64), w2row[d], av);
  float au = embed[(size_t)uid[b]*KD_ + t];
  // seq_embed = x2[n] @ W1^T + embed[node_ids[n]]
  int n = seq_map[bl];
  float xv = x2c[(size_t)(markpos[n]-1)*KD_ + t];
  float se = embed[(size_t)node_ids[n]*KD_ + t];
  const float* w1row = W1 + lane*64;
#pragma unroll 8
  for(int d=0; d<64; d++) se = fmaf(__shfl(xv, d, 64), w1row[d], se);
  float nv  = wred(av*av);
  float nu  = wred(au*au);
  float duv = wred(av*au);
  float dv  = wred(se*av);
  float du  = wred(se*au);
  float ns  = wred(se*se);
  __shared__ float s6[6][4];
  if(lane==0){ s6[0][k]=nv; s6[1][k]=nu; s6[2][k]=duv; s6[3][k]=dv; s6[4][k]=du; s6[5][k]=ns; }
  __syncthreads();
  if(t==0){
    float jv  = expf(-(clk_time[b]-seqs_time[bl]) * (1.0f/1000.0f) * delta[uid[b]]);
    float tau = tau_p[seq_idx[bl]];
    float gam[4], lg[4];
    float m = -1e30f;
#pragma unroll
    for(int kk=0;kk<4;kk++){
      float rnv = fmaxf(sqrtf(s6[0][kk]), 1e-8f);
      float rnu = fmaxf(sqrtf(s6[1][kk]), 1e-8f);
      float ins = 1.f/fmaxf(sqrtf(s6[5][kk]), 1e-8f);
      if(l==0) mu[b*4+kk] = s6[2][kk]/(rnv*rnu);
      gam[kk] = s6[3][kk]*ins/rnv;
      float logit = s6[4][kk]*ins/rnu;
      lg[kk] = (logit + gumbel_at(bl*4+kk))/tau;
      m = fmaxf(m, lg[kk]);
    }
    float es[4], ssum=0.f;
#pragma unroll
    for(int kk=0;kk<4;kk++){ es[kk]=expf(lg[kk]-m); ssum+=es[kk]; }
    float isum = 1.f/ssum;
#pragma unroll
    for(int kk=0;kk<4;kk++)
      atomicAdd(&acc[b*4+kk], jv * gam[kk] * es[kk]*isum);
  }
}

__global__ void finalize(const float* __restrict__ mu, const float* __restrict__ acc,
                         float* __restrict__ out){
  int b = threadIdx.x;
  if(b < B_){
    float s = 0.f;
#pragma unroll
    for(int k=0;k<4;k++) s += mu[b*4+k] + acc[b*4+k];
    out[b] = s * 0.25f;
  }
}

// ---------------- launch ----------------
extern "C" void kernel_launch(void* const* d_in, const int* in_sizes, int n_in,
                              void* d_out, int out_size, void* d_ws, size_t ws_size,
                              hipStream_t stream){
  const float* embed = (const float*)d_in[0];
  const float* delta = (const float*)d_in[1];
  const float* tau_p = (const float*)d_in[2];
  const float* W1    = (const float*)d_in[3];
  const float* W2    = (const float*)d_in[4];
  const float* seqs_time = (const float*)d_in[5];
  const float* clk_time  = (const float*)d_in[6];
  const int* uid      = (const int*)d_in[7];
  const int* sid      = (const int*)d_in[8];
  const int* node_ids = (const int*)d_in[9];
  const int* edge_index = (const int*)d_in[10];
  const int* seq_map  = (const int*)d_in[11];
  const int* tar_map  = (const int*)d_in[12];
  const int* seq_idx  = (const int*)d_in[13];
  const int* seq_len  = (const int*)d_in[14];
  const int* row = edge_index;
  const int* col = edge_index + E_;
  float* out = (float*)d_out;

  // carve: ONE contiguous zero-init region first (acc,ncount,cnt,need,markpos)
  char* wp = (char*)d_ws;
  size_t o = 0;
  auto carve = [&](size_t bytes)->char*{ char* r = wp + o; o = (o + bytes + 255) & ~(size_t)255; return r; };
  float* acc     = (float*)carve((size_t)B_*4*4);
  int*   ncount  = (int*)  carve((size_t)4);
  int*   cnt     = (int*)  carve((size_t)NT_*4);
  int*   need    = (int*)  carve((size_t)NT_*4);
  int*   markpos = (int*)  carve((size_t)NT_*4);
  char*  zero_end = wp + o;
  float* mu      = (float*)carve((size_t)B_*4*4);
  int*   bsum    = (int*)  carve((size_t)256*4);
  int*   nlist   = (int*)  carve((size_t)MAXN_*4);
  float* dinv    = (float*)carve((size_t)NT_*4);
  int*   offs    = (int*)  carve((size_t)NT_*4);
  int*   src_nid = (int*)  carve((size_t)E_*4);
  int*   src_row = (int*)  carve((size_t)E_*4);
  float* wgt     = (float*)carve((size_t)E_*4);
  float* x2c     = (float*)carve((size_t)MAXN_*KD_*4);
  float* x1      = (float*)carve((size_t)NT_*KD_*4);   // 64 MB

  hipMemsetAsync(acc, 0, (size_t)(zero_end - (char*)acc), stream);

  // K1: head-node dedup + degree count
  mark_count<<<(E_+255)/256, 256, 0, stream>>>(seq_map, tar_map, col,
                                               markpos, nlist, ncount, need, cnt);
  // K2..K4: scan -> offs (exclusive), dinv
  block_sums<<<NT_/256, 256, 0, stream>>>(cnt, bsum);
  scan_bsum<<<1, 256, 0, stream>>>(bsum);
  scan_final<<<NT_/256, 256, 0, stream>>>(cnt, bsum, offs, dinv);
  // K5: fill CSR (offs becomes inclusive end)
  fill_csr<<<(E_+255)/256, 256, 0, stream>>>(row, col, node_ids, dinv, markpos,
                                             offs, src_nid, src_row, wgt, need);
  // K6: conv1, only for nodes whose x1 is read downstream
  aggregate1<<<NT_/4, 256, 0, stream>>>((const float4*)embed, offs, cnt, src_nid, wgt,
                                        need, (float4*)x1);
  // K7: conv2 only for head nodes
  conv2_fused<<<MAXN_, 256, 0, stream>>>(x1, offs, cnt, src_row, wgt, nlist, ncount, x2c);
  // K8: scoring head
  head_fused<<<B_*L_, 256, 0, stream>>>(embed, x2c, markpos, W1, W2,
                                        node_ids, seq_map, tar_map, seq_idx, seq_len,
                                        uid, sid, seqs_time, clk_time, tau_p, delta,
                                        mu, acc);
  // K9: finalize
  finalize<<<1, 128, 0, stream>>>(mu, acc, out);
}

// Round 7
// 200.723 us; speedup vs baseline: 11.1239x; 1.0275x over previous
//
#include <hip/hip_runtime.h>
#include <math.h>

// Problem constants (match reference)
#define NT_     64000
#define E_      400000
#define B_      128
#define L_      50
#define KD_     256     // K*D
#define D_      64
#define N_USER_ 100000
#define MAXN_   (B_*L_ + B_)   // 6528 max distinct head nodes

// ---------------- wave helpers ----------------
__device__ __forceinline__ float wred(float v){
#pragma unroll
  for(int s=32;s;s>>=1) v += __shfl_xor(v, s, 64);
  return v;
}
__device__ __forceinline__ int wredi(int v){
#pragma unroll
  for(int s=32;s;s>>=1) v += __shfl_xor(v, s, 64);
  return v;
}

// ---------------- threefry2x32 (JAX key(1) == (0,1)), partitionable XOR-fold ----------------
__device__ __forceinline__ unsigned rotl(unsigned x, int r){ return (x<<r)|(x>>(32-r)); }

__device__ void tf2x32(unsigned c0, unsigned c1, unsigned &o0, unsigned &o1){
  const unsigned k0=0u, k1=1u;
  const unsigned k2=k0^k1^0x1BD11BDAu;
  unsigned x0=c0+k0, x1=c1+k1;
  const int RA[4]={13,15,26,6};
  const int RB[4]={17,29,16,24};
#pragma unroll
  for(int i=0;i<4;i++){ x0+=x1; x1=rotl(x1,RA[i]); x1^=x0; }
  x0+=k1; x1+=k2+1u;
#pragma unroll
  for(int i=0;i<4;i++){ x0+=x1; x1=rotl(x1,RB[i]); x1^=x0; }
  x0+=k2; x1+=k0+2u;
#pragma unroll
  for(int i=0;i<4;i++){ x0+=x1; x1=rotl(x1,RA[i]); x1^=x0; }
  x0+=k0; x1+=k1+3u;
#pragma unroll
  for(int i=0;i<4;i++){ x0+=x1; x1=rotl(x1,RB[i]); x1^=x0; }
  x0+=k1; x1+=k2+4u;
#pragma unroll
  for(int i=0;i<4;i++){ x0+=x1; x1=rotl(x1,RA[i]); x1^=x0; }
  x0+=k2; x1+=k0+5u;
  o0=x0; o1=x1;
}

__device__ float gumbel_at(int idx){
  unsigned o0,o1;
  tf2x32(0u, (unsigned)idx, o0, o1);      // counts uint64 iota: hi=0, lo=idx
  unsigned bits = o0 ^ o1;                 // 32-bit XOR fold (partitionable)
  unsigned fb = (bits>>9) | 0x3f800000u;   // [1,2)
  float f = __uint_as_float(fb) - 1.0f;    // [0,1)
  const float mn=1e-4f, mx=1.0f-1e-4f;
  float u = fmaxf(mn, f*(mx-mn)+mn);
  return -logf(-logf(u));
}

// ---------------- K1: head-node dedup + degree count (fused) ----------------
// markpos encoding: 0 = unassigned, s+1 = slot s (zero-memset friendly)
__global__ void mark_count(const int* __restrict__ seq_map, const int* __restrict__ tar_map,
                           const int* __restrict__ col,
                           int* __restrict__ markpos, int* __restrict__ nlist,
                           int* __restrict__ ncount, int* __restrict__ need,
                           int* __restrict__ cnt){
  int i = blockIdx.x*256 + threadIdx.x;
  if(i < MAXN_){
    int n = (i < B_*L_) ? seq_map[i] : tar_map[i - B_*L_];
    int old = atomicCAS(&markpos[n], 0, -1);
    if(old == 0){
      int s = atomicAdd(ncount, 1);
      nlist[s] = n;
      need[n] = 1;
      __threadfence();
      markpos[n] = s + 1;
    }
  }
  if(i < E_) atomicAdd(&cnt[col[i]], 1);
}

// ---------------- K2: per-256-chunk sums ----------------
__global__ void block_sums(const int* __restrict__ cnt, int* __restrict__ bsum){
  int i = blockIdx.x*256 + threadIdx.x;   // NT_ multiple of 256
  int v = wredi(cnt[i]);
  __shared__ int ws[4];
  if((threadIdx.x&63)==0) ws[threadIdx.x>>6]=v;
  __syncthreads();
  if(threadIdx.x==0) bsum[blockIdx.x]=ws[0]+ws[1]+ws[2]+ws[3];
}

// ---------------- K3: offs (exclusive) + dinv; block base = masked reduce of bsum ----------------
__global__ void scan_final(const int* __restrict__ cnt, const int* __restrict__ bsum,
                           int* __restrict__ offs, float* __restrict__ dinv){
  int t = threadIdx.x;
  int i = blockIdx.x*256 + t;
  int lane = t&63, wv = t>>6;
  __shared__ int sh[8];
  // base = sum of bsum[j] for j < blockIdx.x   (250 block sums, unscanned)
  int bv = (t < blockIdx.x) ? bsum[t] : 0;     // blockIdx.x <= 249 < 256
  int br = wredi(bv);
  if(lane==0) sh[wv] = br;
  __syncthreads();
  int add = sh[0]+sh[1]+sh[2]+sh[3];
  // in-block exclusive scan of cnt
  int v = cnt[i];
  int s = v;
#pragma unroll
  for(int d=1; d<64; d<<=1){ int tt = __shfl_up(s, d, 64); if(lane>=d) s += tt; }
  if(lane==63) sh[4+wv]=s;
  __syncthreads();
  for(int w=0;w<wv;w++) add += sh[4+w];
  offs[i] = add + s - v;
  dinv[i] = (v>0)? (1.0f/sqrtf((float)v)) : 0.0f;
}

// ---------------- K4: fill CSR. slot = atomicAdd(offs[c]); pk=(nid,wgt), src_row ----------------
// After this kernel: offs[c] = INCLUSIVE prefix (end); start = offs[c]-cnt[c].
__global__ void fill_csr(const int* __restrict__ row, const int* __restrict__ col,
                         const int* __restrict__ node_ids, const float* __restrict__ dinv,
                         const int* __restrict__ markpos,
                         int* __restrict__ offs, int2* __restrict__ pk,
                         int* __restrict__ src_row, int* __restrict__ need){
  int e = blockIdx.x*256 + threadIdx.x;
  if(e<E_){
    int c = col[e], r = row[e];
    int slot = atomicAdd(&offs[c], 1);
    float w = dinv[r]*dinv[c]*0.25f;
    pk[slot] = make_int2(node_ids[r], __float_as_int(w));
    src_row[slot] = r;
    if(markpos[c] != 0) need[r] = 1;     // x1[r] will be read by conv2
  }
}

// ---------------- K5: conv1 (filtered): wave-per-node, masked 8-unroll ----------------
__global__ void aggregate1(const float4* __restrict__ embed4, const int* __restrict__ offs,
                           const int* __restrict__ cnt, const int2* __restrict__ pk,
                           const int* __restrict__ need, float4* __restrict__ x14){
  int wv = threadIdx.x>>6, lane = threadIdx.x&63;
  int c = blockIdx.x*4 + wv;
  if(!need[c]) return;                    // x1[c] never read downstream
  int e = offs[c];                        // inclusive end (post-fill)
  int s = e - cnt[c];
  float4 acc = {0.f,0.f,0.f,0.f};
  for(int i=s; i<e; i+=8){
    int   idx[8]; float w[8];
#pragma unroll
    for(int j=0;j<8;j++){
      bool ok = (i+j) < e;
      int2 pr = pk[ok ? (i+j) : s];
      idx[j] = pr.x;
      w[j]   = ok ? __int_as_float(pr.y) : 0.f;
    }
#pragma unroll
    for(int j=0;j<8;j++){
      float4 v = embed4[(size_t)idx[j]*64 + lane];
      acc.x = fmaf(v.x, w[j], acc.x);
      acc.y = fmaf(v.y, w[j], acc.y);
      acc.z = fmaf(v.z, w[j], acc.z);
      acc.w = fmaf(v.w, w[j], acc.w);
    }
  }
  x14[(size_t)c*64+lane] = acc;
}

// ---------------- K6: conv2 fused (only head nodes): z -> softmax -> aggregate ----------------
__global__ void conv2_fused(const float* __restrict__ x1, const int* __restrict__ offs,
                            const int* __restrict__ cnt, const int* __restrict__ src_row,
                            const int2* __restrict__ pk,
                            const int* __restrict__ nlist, const int* __restrict__ ncount,
                            float* __restrict__ x2c){
  int slot = blockIdx.x;
  if(slot >= *ncount) return;
  int c = nlist[slot];
  int t = threadIdx.x, k = t>>6, lane = t&63;
  float tx = tanhf(x1[(size_t)c*KD_ + t]);
  float acc = 0.f;
  __shared__ float zs[4];
  int e = offs[c];
  int s = e - cnt[c];
  for(int i=s;i<e;i++){
    int r = src_row[i];
    float xr = x1[(size_t)r*KD_ + t];
    float zk = wred(xr*tx);               // z[e,k] = dot(x1[row,k,:], tanh(x1[col,k,:]))
    if(lane==0) zs[k] = zk;
    __syncthreads();
    float z0=zs[0], z1=zs[1], z2=zs[2], z3=zs[3];
    // softmax(1+z) over k == softmax(z) (shift-invariant)
    float m = fmaxf(fmaxf(z0,z1), fmaxf(z2,z3));
    float e0=expf(z0-m), e1=expf(z1-m), e2=expf(z2-m), e3=expf(z3-m);
    float wbase = __int_as_float(pk[i].y);
    float inv = (4.f*wbase)/(e0+e1+e2+e3);   // base = 4*wgt
    float w = ((k==0)?e0:(k==1)?e1:(k==2)?e2:e3) * inv;
    acc = fmaf(xr, w, acc);
    __syncthreads();
  }
  x2c[(size_t)slot*KD_ + t] = acc;
}

// ---------------- K7: head (prep_av folded into per-(b,l) block) ----------------
__global__ void head_fused(const float* __restrict__ embed, const float* __restrict__ x2c,
                           const int* __restrict__ markpos,
                           const float* __restrict__ W1, const float* __restrict__ W2,
                           const int* __restrict__ node_ids, const int* __restrict__ seq_map,
                           const int* __restrict__ tar_map, const int* __restrict__ seq_idx,
                           const int* __restrict__ seq_len,
                           const int* __restrict__ uid, const int* __restrict__ sid,
                           const float* __restrict__ seqs_time, const float* __restrict__ clk_time,
                           const float* __restrict__ tau_p, const float* __restrict__ delta,
                           float* __restrict__ mu, float* __restrict__ acc){
  int bl = blockIdx.x;
  int b = bl / L_, l = bl % L_;
  if(l >= seq_len[b]) return;           // masked position contributes exactly 0
  int t = threadIdx.x, k = t>>6, lane = t&63;
  // a_v = x2[tar] @ W2^T + embed[sid+N_USER]   (recomputed per block; 64 shfl-FMAs)
  float xt = x2c[(size_t)(markpos[tar_map[b]]-1)*KD_ + t];
  float av = embed[((size_t)(N_USER_ + sid[b]))*KD_ + t];
  const float* w2row = W2 + lane*64;
#pragma unroll 8
  for(int d=0; d<64; d++) av = fmaf(__shfl(xt, d, 64), w2row[d], av);
  float au = embed[(size_t)uid[b]*KD_ + t];
  // seq_embed = x2[n] @ W1^T + embed[node_ids[n]]
  int n = seq_map[bl];
  float xv = x2c[(size_t)(markpos[n]-1)*KD_ + t];
  float se = embed[(size_t)node_ids[n]*KD_ + t];
  const float* w1row = W1 + lane*64;
#pragma unroll 8
  for(int d=0; d<64; d++) se = fmaf(__shfl(xv, d, 64), w1row[d], se);
  float nv  = wred(av*av);
  float nu  = wred(au*au);
  float duv = wred(av*au);
  float dv  = wred(se*av);
  float du  = wred(se*au);
  float ns  = wred(se*se);
  __shared__ float s6[6][4];
  if(lane==0){ s6[0][k]=nv; s6[1][k]=nu; s6[2][k]=duv; s6[3][k]=dv; s6[4][k]=du; s6[5][k]=ns; }
  __syncthreads();
  if(t==0){
    float jv  = expf(-(clk_time[b]-seqs_time[bl]) * (1.0f/1000.0f) * delta[uid[b]]);
    float tau = tau_p[seq_idx[bl]];
    float gam[4], lg[4];
    float m = -1e30f;
#pragma unroll
    for(int kk=0;kk<4;kk++){
      float rnv = fmaxf(sqrtf(s6[0][kk]), 1e-8f);
      float rnu = fmaxf(sqrtf(s6[1][kk]), 1e-8f);
      float ins = 1.f/fmaxf(sqrtf(s6[5][kk]), 1e-8f);
      if(l==0) mu[b*4+kk] = s6[2][kk]/(rnv*rnu);
      gam[kk] = s6[3][kk]*ins/rnv;
      float logit = s6[4][kk]*ins/rnu;
      lg[kk] = (logit + gumbel_at(bl*4+kk))/tau;
      m = fmaxf(m, lg[kk]);
    }
    float es[4], ssum=0.f;
#pragma unroll
    for(int kk=0;kk<4;kk++){ es[kk]=expf(lg[kk]-m); ssum+=es[kk]; }
    float isum = 1.f/ssum;
#pragma unroll
    for(int kk=0;kk<4;kk++)
      atomicAdd(&acc[b*4+kk], jv * gam[kk] * es[kk]*isum);
  }
}

__global__ void finalize(const float* __restrict__ mu, const float* __restrict__ acc,
                         float* __restrict__ out){
  int b = threadIdx.x;
  if(b < B_){
    float s = 0.f;
#pragma unroll
    for(int k=0;k<4;k++) s += mu[b*4+k] + acc[b*4+k];
    out[b] = s * 0.25f;
  }
}

// ---------------- launch ----------------
extern "C" void kernel_launch(void* const* d_in, const int* in_sizes, int n_in,
                              void* d_out, int out_size, void* d_ws, size_t ws_size,
                              hipStream_t stream){
  const float* embed = (const float*)d_in[0];
  const float* delta = (const float*)d_in[1];
  const float* tau_p = (const float*)d_in[2];
  const float* W1    = (const float*)d_in[3];
  const float* W2    = (const float*)d_in[4];
  const float* seqs_time = (const float*)d_in[5];
  const float* clk_time  = (const float*)d_in[6];
  const int* uid      = (const int*)d_in[7];
  const int* sid      = (const int*)d_in[8];
  const int* node_ids = (const int*)d_in[9];
  const int* edge_index = (const int*)d_in[10];
  const int* seq_map  = (const int*)d_in[11];
  const int* tar_map  = (const int*)d_in[12];
  const int* seq_idx  = (const int*)d_in[13];
  const int* seq_len  = (const int*)d_in[14];
  const int* row = edge_index;
  const int* col = edge_index + E_;
  float* out = (float*)d_out;

  // carve: ONE contiguous zero-init region first (acc,ncount,cnt,need,markpos)
  char* wp = (char*)d_ws;
  size_t o = 0;
  auto carve = [&](size_t bytes)->char*{ char* r = wp + o; o = (o + bytes + 255) & ~(size_t)255; return r; };
  float* acc     = (float*)carve((size_t)B_*4*4);
  int*   ncount  = (int*)  carve((size_t)4);
  int*   cnt     = (int*)  carve((size_t)NT_*4);
  int*   need    = (int*)  carve((size_t)NT_*4);
  int*   markpos = (int*)  carve((size_t)NT_*4);
  char*  zero_end = wp + o;
  float* mu      = (float*)carve((size_t)B_*4*4);
  int*   bsum    = (int*)  carve((size_t)256*4);
  int*   nlist   = (int*)  carve((size_t)MAXN_*4);
  float* dinv    = (float*)carve((size_t)NT_*4);
  int*   offs    = (int*)  carve((size_t)NT_*4);
  int2*  pk      = (int2*) carve((size_t)E_*8);
  int*   src_row = (int*)  carve((size_t)E_*4);
  float* x2c     = (float*)carve((size_t)MAXN_*KD_*4);
  float* x1      = (float*)carve((size_t)NT_*KD_*4);   // 64 MB

  hipMemsetAsync(acc, 0, (size_t)(zero_end - (char*)acc), stream);

  // K1: head-node dedup + degree count
  mark_count<<<(E_+255)/256, 256, 0, stream>>>(seq_map, tar_map, col,
                                               markpos, nlist, ncount, need, cnt);
  // K2,K3: scan -> offs (exclusive), dinv
  block_sums<<<NT_/256, 256, 0, stream>>>(cnt, bsum);
  scan_final<<<NT_/256, 256, 0, stream>>>(cnt, bsum, offs, dinv);
  // K4: fill CSR (offs becomes inclusive end)
  fill_csr<<<(E_+255)/256, 256, 0, stream>>>(row, col, node_ids, dinv, markpos,
                                             offs, pk, src_row, need);
  // K5: conv1, only for nodes whose x1 is read downstream
  aggregate1<<<NT_/4, 256, 0, stream>>>((const float4*)embed, offs, cnt, pk,
                                        need, (float4*)x1);
  // K6: conv2 only for head nodes
  conv2_fused<<<MAXN_, 256, 0, stream>>>(x1, offs, cnt, src_row, pk, nlist, ncount, x2c);
  // K7: scoring head
  head_fused<<<B_*L_, 256, 0, stream>>>(embed, x2c, markpos, W1, W2,
                                        node_ids, seq_map, tar_map, seq_idx, seq_len,
                                        uid, sid, seqs_time, clk_time, tau_p, delta,
                                        mu, acc);
  // K8: finalize
  finalize<<<1, 128, 0, stream>>>(mu, acc, out);
}